// Round 1
// baseline (381.559 us; speedup 1.0000x reference)
//
#include <hip/hip_runtime.h>
#include <stdint.h>

#define CONF 0.96f
#define IOUT 0.45f
#define NA 25200
#define DIM 85
#define NC 80
#define NIMG 8
#define NCAND 2048
#define CAPRAW 4096
#define NDET 300

// ---------------- K0: zero per-image candidate counters ----------------
__global__ void k0_zero(int* __restrict__ cnt) {
    int t = threadIdx.x;
    if (t < NIMG) cnt[t] = 0;
}

// ---------------- K1: threshold filter -> (score, flat_idx) lists ------
__global__ void k1_filter(const float* __restrict__ pred, int* __restrict__ cnt,
                          float* __restrict__ raw_s, int* __restrict__ raw_f) {
    int img = blockIdx.y;
    int a = blockIdx.x * blockDim.x + threadIdx.x;
    if (a >= NA) return;
    const float* p = pred + ((size_t)img * NA + a) * DIM;
    float obj = p[4];
    if (obj > CONF) {
        for (int c = 0; c < NC; ++c) {
            float s = p[5 + c] * obj;
            if (s > CONF) {
                int pos = atomicAdd(&cnt[img], 1);
                if (pos < CAPRAW) {
                    raw_s[img * CAPRAW + pos] = s;
                    raw_f[img * CAPRAW + pos] = a * NC + c;
                }
            }
        }
    }
}

// ---------------- K2: per-image bitonic sort (desc score, asc idx) -----
// Then compute raw + class-offset boxes and areas for the top-2048.
__global__ __launch_bounds__(1024) void k2_sort(
    const float* __restrict__ pred,
    const int* __restrict__ cnt, int* __restrict__ n_arr,
    const float* __restrict__ raw_s, const int* __restrict__ raw_f,
    float* __restrict__ score, int* __restrict__ label,
    float* __restrict__ ox1, float* __restrict__ oy1,
    float* __restrict__ ox2, float* __restrict__ oy2,
    float* __restrict__ area,
    float* __restrict__ rx1, float* __restrict__ ry1,
    float* __restrict__ rx2, float* __restrict__ ry2) {
    __shared__ uint64_t key[CAPRAW];
    int img = blockIdx.x;
    int tid = threadIdx.x;
    int m = cnt[img]; if (m > CAPRAW) m = CAPRAW;
    for (int i = tid; i < CAPRAW; i += 1024) {
        uint64_t k = 0;
        if (i < m) {
            float s = raw_s[img * CAPRAW + i];
            uint32_t f = (uint32_t)raw_f[img * CAPRAW + i];
            // score desc, then flat idx asc (XLA top_k stability)
            k = ((uint64_t)__float_as_uint(s) << 32) | (uint32_t)(~f);
        }
        key[i] = k;
    }
    __syncthreads();
    for (unsigned kk = 2; kk <= CAPRAW; kk <<= 1) {
        for (unsigned j = kk >> 1; j > 0; j >>= 1) {
            for (unsigned i = tid; i < CAPRAW; i += 1024) {
                unsigned ixj = i ^ j;
                if (ixj > i) {
                    uint64_t x = key[i], y = key[ixj];
                    bool up = ((i & kk) == 0);     // overall descending
                    bool sw = up ? (x < y) : (x > y);
                    if (sw) { key[i] = y; key[ixj] = x; }
                }
            }
            __syncthreads();
        }
    }
    int n = m; if (n > NCAND) n = NCAND;
    if (tid == 0) n_arr[img] = n;
    for (int jj = tid; jj < n; jj += 1024) {
        uint64_t k = key[jj];
        float s = __uint_as_float((uint32_t)(k >> 32));
        uint32_t f = ~((uint32_t)k);
        int anchor = (int)(f / NC);
        int lab = (int)(f - (uint32_t)anchor * NC);
        const float* p = pred + ((size_t)img * NA + anchor) * DIM;
        float cx = p[0], cy = p[1], wv = p[2], hv = p[3];
        float x1 = cx - 0.5f * wv, y1 = cy - 0.5f * hv;
        float x2 = cx + 0.5f * wv, y2 = cy + 0.5f * hv;
        float off = (float)lab * 4.0f;
        size_t o = (size_t)img * NCAND + jj;
        score[o] = s; label[o] = lab;
        rx1[o] = x1; ry1[o] = y1; rx2[o] = x2; ry2[o] = y2;
        float o1 = x1 + off, o2 = y1 + off, o3 = x2 + off, o4 = y2 + off;
        ox1[o] = o1; oy1[o] = o2; ox2[o] = o3; oy2[o] = o4;
        area[o] = (o3 - o1) * (o4 - o2);   // same op order as reference
    }
}

// ---------------- K3: suppression bitmask matrix -----------------------
// Interleaved ownership: lane L, bit b  <->  j = L + 64*b (coalesced loads,
// and K4's output phase becomes a plain __ballot per 64-group).
__global__ void k3_mask(const int* __restrict__ n_arr,
                        const float* __restrict__ ox1, const float* __restrict__ oy1,
                        const float* __restrict__ ox2, const float* __restrict__ oy2,
                        const float* __restrict__ area, uint32_t* __restrict__ mask) {
    int img = blockIdx.y;
    int i = blockIdx.x;
    int n = n_arr[img];
    if (i >= n) return;
    int lane = threadIdx.x;
    size_t base = (size_t)img * NCAND;
    float ax1 = ox1[base + i], ay1 = oy1[base + i];
    float ax2 = ox2[base + i], ay2 = oy2[base + i];
    float aar = area[base + i];
    uint32_t word = 0;
    for (int b = 0; b < 32; ++b) {
        int j = lane + (b << 6);
        if (j < n && j > i) {
            float bx1 = ox1[base + j], by1 = oy1[base + j];
            float bx2 = ox2[base + j], by2 = oy2[base + j];
            float bar = area[base + j];
            float ltx = fmaxf(ax1, bx1), lty = fmaxf(ay1, by1);
            float rbx = fminf(ax2, bx2), rby = fminf(ay2, by2);
            float wv = fmaxf(rbx - ltx, 0.0f), hv = fmaxf(rby - lty, 0.0f);
            float inter = wv * hv;
            float iou = inter / (aar + bar - inter + 1e-9f);
            if (iou > IOUT) word |= (1u << b);
        }
    }
    mask[((size_t)img * NCAND + i) * 64 + lane] = word;
}

// ---------------- K4: serial greedy scan + top-300 output --------------
// One wave per image. removed mask lives in one VGPR across 64 lanes.
__global__ void k4_scan(const int* __restrict__ n_arr,
                        const uint32_t* __restrict__ mask,
                        const float* __restrict__ score, const int* __restrict__ label,
                        const float* __restrict__ rx1, const float* __restrict__ ry1,
                        const float* __restrict__ rx2, const float* __restrict__ ry2,
                        float* __restrict__ out) {
    int img = blockIdx.x;
    int lane = threadIdx.x;   // 64 threads = 1 wave
    int n = n_arr[img];
    size_t cbase = (size_t)img * NCAND;
    const uint32_t* rowp = mask + cbase * 64 + lane;
    float* outp = out + (size_t)img * NDET * 6;

    uint32_t removed = 0;
    constexpr int PF = 32;           // prefetch depth (static indices -> regs)
    uint32_t buf[PF];
#pragma unroll
    for (int k = 0; k < PF; ++k) buf[k] = (k < n) ? rowp[(size_t)k * 64] : 0u;
    for (int ib = 0; ib < n; ib += PF) {
#pragma unroll
        for (int k = 0; k < PF; ++k) {
            int i = ib + k;
            uint32_t row = buf[k];
            int pi = i + PF;
            buf[k] = (pi < n) ? rowp[(size_t)pi * 64] : 0u;
            // kept(i)?  bit for i lives at lane (i&63), bit (i>>6). i uniform.
            uint32_t w = (uint32_t)__builtin_amdgcn_readlane((int)removed, i & 63);
            uint32_t kept = ((w >> (i >> 6)) & 1u) ^ 1u;
            removed |= row & (0u - kept);   // row==0 when i>=n -> no-op
        }
    }

    // Emit kept candidates in sorted order (rank = #kept with smaller j).
    int bsum = 0;
    for (int b = 0; b < 32; ++b) {
        int j = lane + (b << 6);
        bool kept = (j < n) && (((removed >> b) & 1u) == 0u);
        unsigned long long m64 = __ballot(kept);
        if (kept) {
            int r = bsum + (int)__popcll(m64 & ((1ull << lane) - 1ull));
            if (r < NDET) {
                float* o = outp + (size_t)r * 6;
                o[0] = rx1[cbase + j]; o[1] = ry1[cbase + j];
                o[2] = rx2[cbase + j]; o[3] = ry2[cbase + j];
                o[4] = score[cbase + j]; o[5] = (float)label[cbase + j];
            }
        }
        bsum += (int)__popcll(m64);
        if (bsum >= NDET) break;         // uniform across the wave
    }
    int nk = bsum < NDET ? bsum : NDET;
    for (int idx = nk * 6 + lane; idx < NDET * 6; idx += 64) outp[idx] = 0.0f;
}

// ---------------- launch ----------------
extern "C" void kernel_launch(void* const* d_in, const int* in_sizes, int n_in,
                              void* d_out, int out_size, void* d_ws, size_t ws_size,
                              hipStream_t stream) {
    const float* pred = (const float*)d_in[0];
    float* out = (float*)d_out;
    char* w = (char*)d_ws;

    const size_t A_CNT = 0;                                // 8 ints
    const size_t A_N   = 256;                              // 8 ints
    const size_t A_RS  = 512;
    const size_t SZ_RAW = (size_t)NIMG * CAPRAW * 4;       // 128 KiB
    const size_t A_RF  = A_RS + SZ_RAW;
    const size_t SA    = A_RF + SZ_RAW;
    const size_t SZ_S  = (size_t)NIMG * NCAND * 4;         // 64 KiB each

    int*   cnt   = (int*)(w + A_CNT);
    int*   n_arr = (int*)(w + A_N);
    float* raw_s = (float*)(w + A_RS);
    int*   raw_f = (int*)(w + A_RF);
    float* score = (float*)(w + SA + 0 * SZ_S);
    int*   label = (int*)(w + SA + 1 * SZ_S);
    float* ox1   = (float*)(w + SA + 2 * SZ_S);
    float* oy1   = (float*)(w + SA + 3 * SZ_S);
    float* ox2   = (float*)(w + SA + 4 * SZ_S);
    float* oy2   = (float*)(w + SA + 5 * SZ_S);
    float* area  = (float*)(w + SA + 6 * SZ_S);
    float* rx1   = (float*)(w + SA + 7 * SZ_S);
    float* ry1   = (float*)(w + SA + 8 * SZ_S);
    float* rx2   = (float*)(w + SA + 9 * SZ_S);
    float* ry2   = (float*)(w + SA + 10 * SZ_S);
    uint32_t* mask = (uint32_t*)(w + SA + 11 * SZ_S);      // 8*2048*64*4 = 4 MiB

    k0_zero<<<1, 64, 0, stream>>>(cnt);
    dim3 g1((NA + 255) / 256, NIMG);
    k1_filter<<<g1, 256, 0, stream>>>(pred, cnt, raw_s, raw_f);
    k2_sort<<<NIMG, 1024, 0, stream>>>(pred, cnt, n_arr, raw_s, raw_f,
        score, label, ox1, oy1, ox2, oy2, area, rx1, ry1, rx2, ry2);
    dim3 g3(NCAND, NIMG);
    k3_mask<<<g3, 64, 0, stream>>>(n_arr, ox1, oy1, ox2, oy2, area, mask);
    k4_scan<<<NIMG, 64, 0, stream>>>(n_arr, mask, score, label,
        rx1, ry1, rx2, ry2, out);
}

// Round 2
// 379.869 us; speedup vs baseline: 1.0044x; 1.0044x over previous
//
#include <hip/hip_runtime.h>
#include <stdint.h>

#define CONF 0.96f
#define IOUT 0.45f
#define NA 25200
#define DIM 85
#define NC 80
#define NIMG 8
#define NCAND 2048
#define CAPRAW 4096
#define NDET 300

// ---------------- K0: zero per-image candidate counters ----------------
__global__ void k0_zero(int* __restrict__ cnt) {
    int t = threadIdx.x;
    if (t < NIMG) cnt[t] = 0;
}

// ---------------- K1: coalesced filter via LDS staging -----------------
// 128 anchors/block staged as float4 (42.5 KB LDS), then 256 threads sweep
// the 128x80 (anchor,class) grid from LDS. Reads the WHOLE input (68.5 MB
// coalesced ~= 11 us) instead of strided obj-only loads (153 us measured).
#define APB 128                       // anchors per block
__global__ __launch_bounds__(256) void k1_filter(
    const float* __restrict__ pred, int* __restrict__ cnt,
    float* __restrict__ raw_s, int* __restrict__ raw_f) {
    __shared__ float lds[APB * DIM];  // 128*85*4 = 43520 B
    int tid = threadIdx.x;
    int ga0 = blockIdx.x * APB;       // global anchor base (images concatenated)

    // phase 1: coalesced float4 copy. APB*DIM = 10880 floats = 2720 float4.
    const float4* src = (const float4*)(pred + (size_t)ga0 * DIM);
    float4* dst = (float4*)lds;
    for (int i = tid; i < (APB * DIM / 4); i += 256) dst[i] = src[i];
    __syncthreads();

    // phase 2: 128*80 = 10240 work items over 256 threads (40 iters).
    for (int it = 0; it < (APB * NC / 256); ++it) {
        int w = tid + it * 256;
        int al = w / NC;              // local anchor
        int c = w - al * NC;          // class
        float obj = lds[al * DIM + 4];
        float s = lds[al * DIM + 5 + c] * obj;
        if (s > CONF && obj > CONF) {
            int ga = ga0 + al;
            int img = ga / NA;
            int a = ga - img * NA;
            int pos = atomicAdd(&cnt[img], 1);
            if (pos < CAPRAW) {
                raw_s[img * CAPRAW + pos] = s;
                raw_f[img * CAPRAW + pos] = a * NC + c;
            }
        }
    }
}

// ---------------- K2: per-image bitonic sort (desc score, asc idx) -----
// Then compute raw + class-offset boxes and areas for the top-2048.
__global__ __launch_bounds__(1024) void k2_sort(
    const float* __restrict__ pred,
    const int* __restrict__ cnt, int* __restrict__ n_arr,
    const float* __restrict__ raw_s, const int* __restrict__ raw_f,
    float* __restrict__ score, int* __restrict__ label,
    float* __restrict__ ox1, float* __restrict__ oy1,
    float* __restrict__ ox2, float* __restrict__ oy2,
    float* __restrict__ area,
    float* __restrict__ rx1, float* __restrict__ ry1,
    float* __restrict__ rx2, float* __restrict__ ry2) {
    __shared__ uint64_t key[CAPRAW];
    int img = blockIdx.x;
    int tid = threadIdx.x;
    int m = cnt[img]; if (m > CAPRAW) m = CAPRAW;
    for (int i = tid; i < CAPRAW; i += 1024) {
        uint64_t k = 0;
        if (i < m) {
            float s = raw_s[img * CAPRAW + i];
            uint32_t f = (uint32_t)raw_f[img * CAPRAW + i];
            // score desc, then flat idx asc (XLA top_k stability)
            k = ((uint64_t)__float_as_uint(s) << 32) | (uint32_t)(~f);
        }
        key[i] = k;
    }
    __syncthreads();
    for (unsigned kk = 2; kk <= CAPRAW; kk <<= 1) {
        for (unsigned j = kk >> 1; j > 0; j >>= 1) {
            for (unsigned i = tid; i < CAPRAW; i += 1024) {
                unsigned ixj = i ^ j;
                if (ixj > i) {
                    uint64_t x = key[i], y = key[ixj];
                    bool up = ((i & kk) == 0);     // overall descending
                    bool sw = up ? (x < y) : (x > y);
                    if (sw) { key[i] = y; key[ixj] = x; }
                }
            }
            __syncthreads();
        }
    }
    int n = m; if (n > NCAND) n = NCAND;
    if (tid == 0) n_arr[img] = n;
    for (int jj = tid; jj < n; jj += 1024) {
        uint64_t k = key[jj];
        float s = __uint_as_float((uint32_t)(k >> 32));
        uint32_t f = ~((uint32_t)k);
        int anchor = (int)(f / NC);
        int lab = (int)(f - (uint32_t)anchor * NC);
        const float* p = pred + ((size_t)img * NA + anchor) * DIM;
        float cx = p[0], cy = p[1], wv = p[2], hv = p[3];
        float x1 = cx - 0.5f * wv, y1 = cy - 0.5f * hv;
        float x2 = cx + 0.5f * wv, y2 = cy + 0.5f * hv;
        float off = (float)lab * 4.0f;
        size_t o = (size_t)img * NCAND + jj;
        score[o] = s; label[o] = lab;
        rx1[o] = x1; ry1[o] = y1; rx2[o] = x2; ry2[o] = y2;
        float o1 = x1 + off, o2 = y1 + off, o3 = x2 + off, o4 = y2 + off;
        ox1[o] = o1; oy1[o] = o2; ox2[o] = o3; oy2[o] = o4;
        area[o] = (o3 - o1) * (o4 - o2);   // same op order as reference
    }
}

// ---------------- K3: suppression bitmask matrix -----------------------
// Interleaved ownership: lane L, bit b  <->  j = L + 64*b (coalesced loads,
// and K4's output phase becomes a plain __ballot per 64-group).
__global__ void k3_mask(const int* __restrict__ n_arr,
                        const float* __restrict__ ox1, const float* __restrict__ oy1,
                        const float* __restrict__ ox2, const float* __restrict__ oy2,
                        const float* __restrict__ area, uint32_t* __restrict__ mask) {
    int img = blockIdx.y;
    int i = blockIdx.x;
    int n = n_arr[img];
    if (i >= n) return;
    int lane = threadIdx.x;
    size_t base = (size_t)img * NCAND;
    float ax1 = ox1[base + i], ay1 = oy1[base + i];
    float ax2 = ox2[base + i], ay2 = oy2[base + i];
    float aar = area[base + i];
    uint32_t word = 0;
    for (int b = 0; b < 32; ++b) {
        int j = lane + (b << 6);
        if (j < n && j > i) {
            float bx1 = ox1[base + j], by1 = oy1[base + j];
            float bx2 = ox2[base + j], by2 = oy2[base + j];
            float bar = area[base + j];
            float ltx = fmaxf(ax1, bx1), lty = fmaxf(ay1, by1);
            float rbx = fminf(ax2, bx2), rby = fminf(ay2, by2);
            float wv = fmaxf(rbx - ltx, 0.0f), hv = fmaxf(rby - lty, 0.0f);
            float inter = wv * hv;
            float iou = inter / (aar + bar - inter + 1e-9f);
            if (iou > IOUT) word |= (1u << b);
        }
    }
    mask[((size_t)img * NCAND + i) * 64 + lane] = word;
}

// ---------------- K4: serial greedy scan + top-300 output --------------
// One wave per image. removed mask lives in one VGPR across 64 lanes.
__global__ void k4_scan(const int* __restrict__ n_arr,
                        const uint32_t* __restrict__ mask,
                        const float* __restrict__ score, const int* __restrict__ label,
                        const float* __restrict__ rx1, const float* __restrict__ ry1,
                        const float* __restrict__ rx2, const float* __restrict__ ry2,
                        float* __restrict__ out) {
    int img = blockIdx.x;
    int lane = threadIdx.x;   // 64 threads = 1 wave
    int n = n_arr[img];
    size_t cbase = (size_t)img * NCAND;
    const uint32_t* rowp = mask + cbase * 64 + lane;
    float* outp = out + (size_t)img * NDET * 6;

    uint32_t removed = 0;
    constexpr int PF = 32;           // prefetch depth (static indices -> regs)
    uint32_t buf[PF];
#pragma unroll
    for (int k = 0; k < PF; ++k) buf[k] = (k < n) ? rowp[(size_t)k * 64] : 0u;
    for (int ib = 0; ib < n; ib += PF) {
#pragma unroll
        for (int k = 0; k < PF; ++k) {
            int i = ib + k;
            uint32_t row = buf[k];
            int pi = i + PF;
            buf[k] = (pi < n) ? rowp[(size_t)pi * 64] : 0u;
            // kept(i)?  bit for i lives at lane (i&63), bit (i>>6). i uniform.
            uint32_t w = (uint32_t)__builtin_amdgcn_readlane((int)removed, i & 63);
            uint32_t kept = ((w >> (i >> 6)) & 1u) ^ 1u;
            removed |= row & (0u - kept);   // row==0 when i>=n -> no-op
        }
    }

    // Emit kept candidates in sorted order (rank = #kept with smaller j).
    int bsum = 0;
    for (int b = 0; b < 32; ++b) {
        int j = lane + (b << 6);
        bool kept = (j < n) && (((removed >> b) & 1u) == 0u);
        unsigned long long m64 = __ballot(kept);
        if (kept) {
            int r = bsum + (int)__popcll(m64 & ((1ull << lane) - 1ull));
            if (r < NDET) {
                float* o = outp + (size_t)r * 6;
                o[0] = rx1[cbase + j]; o[1] = ry1[cbase + j];
                o[2] = rx2[cbase + j]; o[3] = ry2[cbase + j];
                o[4] = score[cbase + j]; o[5] = (float)label[cbase + j];
            }
        }
        bsum += (int)__popcll(m64);
        if (bsum >= NDET) break;         // uniform across the wave
    }
    int nk = bsum < NDET ? bsum : NDET;
    for (int idx = nk * 6 + lane; idx < NDET * 6; idx += 64) outp[idx] = 0.0f;
}

// ---------------- launch ----------------
extern "C" void kernel_launch(void* const* d_in, const int* in_sizes, int n_in,
                              void* d_out, int out_size, void* d_ws, size_t ws_size,
                              hipStream_t stream) {
    const float* pred = (const float*)d_in[0];
    float* out = (float*)d_out;
    char* w = (char*)d_ws;

    const size_t A_CNT = 0;                                // 8 ints
    const size_t A_N   = 256;                              // 8 ints
    const size_t A_RS  = 512;
    const size_t SZ_RAW = (size_t)NIMG * CAPRAW * 4;       // 128 KiB
    const size_t A_RF  = A_RS + SZ_RAW;
    const size_t SA    = A_RF + SZ_RAW;
    const size_t SZ_S  = (size_t)NIMG * NCAND * 4;         // 64 KiB each

    int*   cnt   = (int*)(w + A_CNT);
    int*   n_arr = (int*)(w + A_N);
    float* raw_s = (float*)(w + A_RS);
    int*   raw_f = (int*)(w + A_RF);
    float* score = (float*)(w + SA + 0 * SZ_S);
    int*   label = (int*)(w + SA + 1 * SZ_S);
    float* ox1   = (float*)(w + SA + 2 * SZ_S);
    float* oy1   = (float*)(w + SA + 3 * SZ_S);
    float* ox2   = (float*)(w + SA + 4 * SZ_S);
    float* oy2   = (float*)(w + SA + 5 * SZ_S);
    float* area  = (float*)(w + SA + 6 * SZ_S);
    float* rx1   = (float*)(w + SA + 7 * SZ_S);
    float* ry1   = (float*)(w + SA + 8 * SZ_S);
    float* rx2   = (float*)(w + SA + 9 * SZ_S);
    float* ry2   = (float*)(w + SA + 10 * SZ_S);
    uint32_t* mask = (uint32_t*)(w + SA + 11 * SZ_S);      // 8*2048*64*4 = 4 MiB

    k0_zero<<<1, 64, 0, stream>>>(cnt);
    k1_filter<<<(NIMG * NA) / APB, 256, 0, stream>>>(pred, cnt, raw_s, raw_f);
    k2_sort<<<NIMG, 1024, 0, stream>>>(pred, cnt, n_arr, raw_s, raw_f,
        score, label, ox1, oy1, ox2, oy2, area, rx1, ry1, rx2, ry2);
    dim3 g3(NCAND, NIMG);
    k3_mask<<<g3, 64, 0, stream>>>(n_arr, ox1, oy1, ox2, oy2, area, mask);
    k4_scan<<<NIMG, 64, 0, stream>>>(n_arr, mask, score, label,
        rx1, ry1, rx2, ry2, out);
}

// Round 3
// 245.664 us; speedup vs baseline: 1.5532x; 1.5463x over previous
//
#include <hip/hip_runtime.h>
#include <stdint.h>

#define CONF 0.96f
#define IOUT 0.45f
#define NA 25200
#define DIM 85
#define NC 80
#define NIMG 8
#define NCAND 2048
#define CAPRAW 4096
#define NDET 300
#define CSTRIDE 32                    // cnt[img*CSTRIDE]: 128 B between counters

// ---------------- K0: zero per-image candidate counters ----------------
__global__ void k0_zero(int* __restrict__ cnt) {
    cnt[threadIdx.x] = 0;             // launch 256 = NIMG*CSTRIDE
}

// ---------------- K1: coalesced filter, block-aggregated atomics -------
// 112 anchors/block (divides 25200 -> single-image blocks) staged via
// float4 into LDS; candidates buffered in LDS (LDS atomics), ONE global
// atomicAdd per block reserves the slot range. Round1/2 were bound by
// ~13K same-cache-line cross-XCD atomics (~12ns each ~= 156us, invariant
// across both structures); this drops to ~225 per image on separate lines.
#define APB 112
#define BCAP 256                      // block candidate cap (E=7.3, P(>256)~0)
__global__ __launch_bounds__(256) void k1_filter(
    const float* __restrict__ pred, int* __restrict__ cnt,
    float* __restrict__ raw_s, int* __restrict__ raw_f) {
    __shared__ float lds[APB * DIM];  // 38080 B
    __shared__ float l_s[BCAP];
    __shared__ int   l_f[BCAP];
    __shared__ int   l_cnt, l_base;
    int tid = threadIdx.x;
    int img = blockIdx.y;
    int a0 = blockIdx.x * APB;        // anchor base within this image
    if (tid == 0) l_cnt = 0;

    const float4* src = (const float4*)(pred + ((size_t)img * NA + a0) * DIM);
    float4* dst = (float4*)lds;
    for (int i = tid; i < (APB * DIM / 4); i += 256) dst[i] = src[i];
    __syncthreads();

    // 112*80 = 8960 items over 256 threads (35 iters)
    for (int it = 0; it < (APB * NC / 256); ++it) {
        int w = tid + it * 256;
        int al = w / NC;              // local anchor
        int c = w - al * NC;          // class
        float obj = lds[al * DIM + 4];
        float s = lds[al * DIM + 5 + c] * obj;
        if (s > CONF && obj > CONF) {
            int p = atomicAdd(&l_cnt, 1);          // LDS atomic: cheap
            if (p < BCAP) { l_s[p] = s; l_f[p] = (a0 + al) * NC + c; }
        }
    }
    __syncthreads();
    int c = l_cnt; if (c > BCAP) c = BCAP;
    if (tid == 0) l_base = c ? atomicAdd(&cnt[img * CSTRIDE], c) : 0;
    __syncthreads();
    int base = l_base;
    for (int i = tid; i < c; i += 256) {
        int pos = base + i;
        if (pos < CAPRAW) {
            raw_s[img * CAPRAW + pos] = l_s[i];
            raw_f[img * CAPRAW + pos] = l_f[i];
        }
    }
}

// ---------------- K2: per-image bitonic sort (desc score, asc idx) -----
// Then compute raw + class-offset boxes and areas for the top-2048.
__global__ __launch_bounds__(1024) void k2_sort(
    const float* __restrict__ pred,
    const int* __restrict__ cnt, int* __restrict__ n_arr,
    const float* __restrict__ raw_s, const int* __restrict__ raw_f,
    float* __restrict__ score, int* __restrict__ label,
    float* __restrict__ ox1, float* __restrict__ oy1,
    float* __restrict__ ox2, float* __restrict__ oy2,
    float* __restrict__ area,
    float* __restrict__ rx1, float* __restrict__ ry1,
    float* __restrict__ rx2, float* __restrict__ ry2) {
    __shared__ uint64_t key[CAPRAW];
    int img = blockIdx.x;
    int tid = threadIdx.x;
    int m = cnt[img * CSTRIDE]; if (m > CAPRAW) m = CAPRAW;
    for (int i = tid; i < CAPRAW; i += 1024) {
        uint64_t k = 0;
        if (i < m) {
            float s = raw_s[img * CAPRAW + i];
            uint32_t f = (uint32_t)raw_f[img * CAPRAW + i];
            // score desc, then flat idx asc (XLA top_k stability)
            k = ((uint64_t)__float_as_uint(s) << 32) | (uint32_t)(~f);
        }
        key[i] = k;
    }
    __syncthreads();
    for (unsigned kk = 2; kk <= CAPRAW; kk <<= 1) {
        for (unsigned j = kk >> 1; j > 0; j >>= 1) {
            for (unsigned i = tid; i < CAPRAW; i += 1024) {
                unsigned ixj = i ^ j;
                if (ixj > i) {
                    uint64_t x = key[i], y = key[ixj];
                    bool up = ((i & kk) == 0);     // overall descending
                    bool sw = up ? (x < y) : (x > y);
                    if (sw) { key[i] = y; key[ixj] = x; }
                }
            }
            __syncthreads();
        }
    }
    int n = m; if (n > NCAND) n = NCAND;
    if (tid == 0) n_arr[img] = n;
    for (int jj = tid; jj < n; jj += 1024) {
        uint64_t k = key[jj];
        float s = __uint_as_float((uint32_t)(k >> 32));
        uint32_t f = ~((uint32_t)k);
        int anchor = (int)(f / NC);
        int lab = (int)(f - (uint32_t)anchor * NC);
        const float* p = pred + ((size_t)img * NA + anchor) * DIM;
        float cx = p[0], cy = p[1], wv = p[2], hv = p[3];
        float x1 = cx - 0.5f * wv, y1 = cy - 0.5f * hv;
        float x2 = cx + 0.5f * wv, y2 = cy + 0.5f * hv;
        float off = (float)lab * 4.0f;
        size_t o = (size_t)img * NCAND + jj;
        score[o] = s; label[o] = lab;
        rx1[o] = x1; ry1[o] = y1; rx2[o] = x2; ry2[o] = y2;
        float o1 = x1 + off, o2 = y1 + off, o3 = x2 + off, o4 = y2 + off;
        ox1[o] = o1; oy1[o] = o2; ox2[o] = o3; oy2[o] = o4;
        area[o] = (o3 - o1) * (o4 - o2);   // same op order as reference
    }
}

// ---------------- K3: suppression bitmask matrix -----------------------
// Interleaved ownership: lane L, bit b  <->  j = L + 64*b (coalesced loads,
// and K4's output phase becomes a plain __ballot per 64-group).
__global__ void k3_mask(const int* __restrict__ n_arr,
                        const float* __restrict__ ox1, const float* __restrict__ oy1,
                        const float* __restrict__ ox2, const float* __restrict__ oy2,
                        const float* __restrict__ area, uint32_t* __restrict__ mask) {
    int img = blockIdx.y;
    int i = blockIdx.x;
    int n = n_arr[img];
    if (i >= n) return;
    int lane = threadIdx.x;
    size_t base = (size_t)img * NCAND;
    float ax1 = ox1[base + i], ay1 = oy1[base + i];
    float ax2 = ox2[base + i], ay2 = oy2[base + i];
    float aar = area[base + i];
    uint32_t word = 0;
    for (int b = 0; b < 32; ++b) {
        int j = lane + (b << 6);
        if (j < n && j > i) {
            float bx1 = ox1[base + j], by1 = oy1[base + j];
            float bx2 = ox2[base + j], by2 = oy2[base + j];
            float bar = area[base + j];
            float ltx = fmaxf(ax1, bx1), lty = fmaxf(ay1, by1);
            float rbx = fminf(ax2, bx2), rby = fminf(ay2, by2);
            float wv = fmaxf(rbx - ltx, 0.0f), hv = fmaxf(rby - lty, 0.0f);
            float inter = wv * hv;
            float iou = inter / (aar + bar - inter + 1e-9f);
            if (iou > IOUT) word |= (1u << b);
        }
    }
    mask[((size_t)img * NCAND + i) * 64 + lane] = word;
}

// ---------------- K4: serial greedy scan + top-300 output --------------
// One wave per image. removed mask lives in one VGPR across 64 lanes.
__global__ void k4_scan(const int* __restrict__ n_arr,
                        const uint32_t* __restrict__ mask,
                        const float* __restrict__ score, const int* __restrict__ label,
                        const float* __restrict__ rx1, const float* __restrict__ ry1,
                        const float* __restrict__ rx2, const float* __restrict__ ry2,
                        float* __restrict__ out) {
    int img = blockIdx.x;
    int lane = threadIdx.x;   // 64 threads = 1 wave
    int n = n_arr[img];
    size_t cbase = (size_t)img * NCAND;
    const uint32_t* rowp = mask + cbase * 64 + lane;
    float* outp = out + (size_t)img * NDET * 6;

    uint32_t removed = 0;
    constexpr int PF = 32;           // prefetch depth (static indices -> regs)
    uint32_t buf[PF];
#pragma unroll
    for (int k = 0; k < PF; ++k) buf[k] = (k < n) ? rowp[(size_t)k * 64] : 0u;
    for (int ib = 0; ib < n; ib += PF) {
#pragma unroll
        for (int k = 0; k < PF; ++k) {
            int i = ib + k;
            uint32_t row = buf[k];
            int pi = i + PF;
            buf[k] = (pi < n) ? rowp[(size_t)pi * 64] : 0u;
            // kept(i)?  bit for i lives at lane (i&63), bit (i>>6). i uniform.
            uint32_t w = (uint32_t)__builtin_amdgcn_readlane((int)removed, i & 63);
            uint32_t kept = ((w >> (i >> 6)) & 1u) ^ 1u;
            removed |= row & (0u - kept);   // row==0 when i>=n -> no-op
        }
    }

    // Emit kept candidates in sorted order (rank = #kept with smaller j).
    int bsum = 0;
    for (int b = 0; b < 32; ++b) {
        int j = lane + (b << 6);
        bool kept = (j < n) && (((removed >> b) & 1u) == 0u);
        unsigned long long m64 = __ballot(kept);
        if (kept) {
            int r = bsum + (int)__popcll(m64 & ((1ull << lane) - 1ull));
            if (r < NDET) {
                float* o = outp + (size_t)r * 6;
                o[0] = rx1[cbase + j]; o[1] = ry1[cbase + j];
                o[2] = rx2[cbase + j]; o[3] = ry2[cbase + j];
                o[4] = score[cbase + j]; o[5] = (float)label[cbase + j];
            }
        }
        bsum += (int)__popcll(m64);
        if (bsum >= NDET) break;         // uniform across the wave
    }
    int nk = bsum < NDET ? bsum : NDET;
    for (int idx = nk * 6 + lane; idx < NDET * 6; idx += 64) outp[idx] = 0.0f;
}

// ---------------- launch ----------------
extern "C" void kernel_launch(void* const* d_in, const int* in_sizes, int n_in,
                              void* d_out, int out_size, void* d_ws, size_t ws_size,
                              hipStream_t stream) {
    const float* pred = (const float*)d_in[0];
    float* out = (float*)d_out;
    char* w = (char*)d_ws;

    const size_t A_CNT = 0;                                // 8*32 ints (padded)
    const size_t A_N   = 1024;                             // 8 ints
    const size_t A_RS  = 1280;
    const size_t SZ_RAW = (size_t)NIMG * CAPRAW * 4;       // 128 KiB
    const size_t A_RF  = A_RS + SZ_RAW;
    const size_t SA    = A_RF + SZ_RAW;
    const size_t SZ_S  = (size_t)NIMG * NCAND * 4;         // 64 KiB each

    int*   cnt   = (int*)(w + A_CNT);
    int*   n_arr = (int*)(w + A_N);
    float* raw_s = (float*)(w + A_RS);
    int*   raw_f = (int*)(w + A_RF);
    float* score = (float*)(w + SA + 0 * SZ_S);
    int*   label = (int*)(w + SA + 1 * SZ_S);
    float* ox1   = (float*)(w + SA + 2 * SZ_S);
    float* oy1   = (float*)(w + SA + 3 * SZ_S);
    float* ox2   = (float*)(w + SA + 4 * SZ_S);
    float* oy2   = (float*)(w + SA + 5 * SZ_S);
    float* area  = (float*)(w + SA + 6 * SZ_S);
    float* rx1   = (float*)(w + SA + 7 * SZ_S);
    float* ry1   = (float*)(w + SA + 8 * SZ_S);
    float* rx2   = (float*)(w + SA + 9 * SZ_S);
    float* ry2   = (float*)(w + SA + 10 * SZ_S);
    uint32_t* mask = (uint32_t*)(w + SA + 11 * SZ_S);      // 8*2048*64*4 = 4 MiB

    k0_zero<<<1, NIMG * CSTRIDE, 0, stream>>>(cnt);
    dim3 g1(NA / APB, NIMG);                               // 225 x 8
    k1_filter<<<g1, 256, 0, stream>>>(pred, cnt, raw_s, raw_f);
    k2_sort<<<NIMG, 1024, 0, stream>>>(pred, cnt, n_arr, raw_s, raw_f,
        score, label, ox1, oy1, ox2, oy2, area, rx1, ry1, rx2, ry2);
    dim3 g3(NCAND, NIMG);
    k3_mask<<<g3, 64, 0, stream>>>(n_arr, ox1, oy1, ox2, oy2, area, mask);
    k4_scan<<<NIMG, 64, 0, stream>>>(n_arr, mask, score, label,
        rx1, ry1, rx2, ry2, out);
}

// Round 4
// 196.291 us; speedup vs baseline: 1.9438x; 1.2515x over previous
//
#include <hip/hip_runtime.h>
#include <stdint.h>

#define CONF 0.96f
#define IOUT 0.45f
#define NA 25200
#define DIM 85
#define NC 80
#define NIMG 8
#define NCAND 2048
#define CAPRAW 4096
#define NDET 300
#define CSTRIDE 32                    // cnt[img*CSTRIDE]: 128 B between counters

// ---------------- K0: zero per-image candidate counters ----------------
__global__ void k0_zero(int* __restrict__ cnt) {
    cnt[threadIdx.x] = 0;             // launch 256 = NIMG*CSTRIDE
}

// ---------------- K1: coalesced filter, block-aggregated atomics -------
#define APB 112
#define BCAP 256                      // block candidate cap (E=7.3, P(>256)~0)
__global__ __launch_bounds__(256) void k1_filter(
    const float* __restrict__ pred, int* __restrict__ cnt,
    float* __restrict__ raw_s, int* __restrict__ raw_f) {
    __shared__ float lds[APB * DIM];  // 38080 B
    __shared__ float l_s[BCAP];
    __shared__ int   l_f[BCAP];
    __shared__ int   l_cnt, l_base;
    int tid = threadIdx.x;
    int img = blockIdx.y;
    int a0 = blockIdx.x * APB;        // anchor base within this image
    if (tid == 0) l_cnt = 0;

    const float4* src = (const float4*)(pred + ((size_t)img * NA + a0) * DIM);
    float4* dst = (float4*)lds;
    for (int i = tid; i < (APB * DIM / 4); i += 256) dst[i] = src[i];
    __syncthreads();

    // 112*80 = 8960 items over 256 threads (35 iters)
    for (int it = 0; it < (APB * NC / 256); ++it) {
        int w = tid + it * 256;
        int al = w / NC;              // local anchor
        int c = w - al * NC;          // class
        float obj = lds[al * DIM + 4];
        float s = lds[al * DIM + 5 + c] * obj;
        if (s > CONF && obj > CONF) {
            int p = atomicAdd(&l_cnt, 1);          // LDS atomic: cheap
            if (p < BCAP) { l_s[p] = s; l_f[p] = (a0 + al) * NC + c; }
        }
    }
    __syncthreads();
    int c = l_cnt; if (c > BCAP) c = BCAP;
    if (tid == 0) l_base = c ? atomicAdd(&cnt[img * CSTRIDE], c) : 0;
    __syncthreads();
    int base = l_base;
    for (int i = tid; i < c; i += 256) {
        int pos = base + i;
        if (pos < CAPRAW) {
            raw_s[img * CAPRAW + pos] = l_s[i];
            raw_f[img * CAPRAW + pos] = l_f[i];
        }
    }
}

// ---------------- K2: per-image bitonic sort (desc score, asc idx) -----
__global__ __launch_bounds__(1024) void k2_sort(
    const float* __restrict__ pred,
    const int* __restrict__ cnt, int* __restrict__ n_arr,
    const float* __restrict__ raw_s, const int* __restrict__ raw_f,
    float* __restrict__ score, int* __restrict__ label,
    float* __restrict__ ox1, float* __restrict__ oy1,
    float* __restrict__ ox2, float* __restrict__ oy2,
    float* __restrict__ area,
    float* __restrict__ rx1, float* __restrict__ ry1,
    float* __restrict__ rx2, float* __restrict__ ry2) {
    __shared__ uint64_t key[CAPRAW];
    int img = blockIdx.x;
    int tid = threadIdx.x;
    int m = cnt[img * CSTRIDE]; if (m > CAPRAW) m = CAPRAW;
    for (int i = tid; i < CAPRAW; i += 1024) {
        uint64_t k = 0;
        if (i < m) {
            float s = raw_s[img * CAPRAW + i];
            uint32_t f = (uint32_t)raw_f[img * CAPRAW + i];
            // score desc, then flat idx asc (XLA top_k stability)
            k = ((uint64_t)__float_as_uint(s) << 32) | (uint32_t)(~f);
        }
        key[i] = k;
    }
    __syncthreads();
    for (unsigned kk = 2; kk <= CAPRAW; kk <<= 1) {
        for (unsigned j = kk >> 1; j > 0; j >>= 1) {
            for (unsigned i = tid; i < CAPRAW; i += 1024) {
                unsigned ixj = i ^ j;
                if (ixj > i) {
                    uint64_t x = key[i], y = key[ixj];
                    bool up = ((i & kk) == 0);     // overall descending
                    bool sw = up ? (x < y) : (x > y);
                    if (sw) { key[i] = y; key[ixj] = x; }
                }
            }
            __syncthreads();
        }
    }
    int n = m; if (n > NCAND) n = NCAND;
    if (tid == 0) n_arr[img] = n;
    for (int jj = tid; jj < n; jj += 1024) {
        uint64_t k = key[jj];
        float s = __uint_as_float((uint32_t)(k >> 32));
        uint32_t f = ~((uint32_t)k);
        int anchor = (int)(f / NC);
        int lab = (int)(f - (uint32_t)anchor * NC);
        const float* p = pred + ((size_t)img * NA + anchor) * DIM;
        float cx = p[0], cy = p[1], wv = p[2], hv = p[3];
        float x1 = cx - 0.5f * wv, y1 = cy - 0.5f * hv;
        float x2 = cx + 0.5f * wv, y2 = cy + 0.5f * hv;
        float off = (float)lab * 4.0f;
        size_t o = (size_t)img * NCAND + jj;
        score[o] = s; label[o] = lab;
        rx1[o] = x1; ry1[o] = y1; rx2[o] = x2; ry2[o] = y2;
        float o1 = x1 + off, o2 = y1 + off, o3 = x2 + off, o4 = y2 + off;
        ox1[o] = o1; oy1[o] = o2; ox2[o] = o3; oy2[o] = o4;
        area[o] = (o3 - o1) * (o4 - o2);   // same op order as reference
    }
}

// ---------------- K3: suppression bitmask matrix -----------------------
// Interleaved ownership: lane L, bit b  <->  j = L + 64*b.
// Rows i >= n are ZERO-FILLED (k4 loads unconditionally).
__global__ void k3_mask(const int* __restrict__ n_arr,
                        const float* __restrict__ ox1, const float* __restrict__ oy1,
                        const float* __restrict__ ox2, const float* __restrict__ oy2,
                        const float* __restrict__ area, uint32_t* __restrict__ mask) {
    int img = blockIdx.y;
    int i = blockIdx.x;
    int n = n_arr[img];
    int lane = threadIdx.x;
    size_t base = (size_t)img * NCAND;
    uint32_t word = 0;
    if (i < n) {
        float ax1 = ox1[base + i], ay1 = oy1[base + i];
        float ax2 = ox2[base + i], ay2 = oy2[base + i];
        float aar = area[base + i];
        for (int b = 0; b < 32; ++b) {
            int j = lane + (b << 6);
            if (j < n && j > i) {
                float bx1 = ox1[base + j], by1 = oy1[base + j];
                float bx2 = ox2[base + j], by2 = oy2[base + j];
                float bar = area[base + j];
                float ltx = fmaxf(ax1, bx1), lty = fmaxf(ay1, by1);
                float rbx = fminf(ax2, bx2), rby = fminf(ay2, by2);
                float wv = fmaxf(rbx - ltx, 0.0f), hv = fmaxf(rby - lty, 0.0f);
                float inter = wv * hv;
                float iou = inter / (aar + bar - inter + 1e-9f);
                if (iou > IOUT) word |= (1u << b);
            }
        }
    }
    mask[((size_t)img * NCAND + i) * 64 + lane] = word;
}

// ---------------- K4: serial greedy scan + top-300 output --------------
// One wave per image. removed mask lives in one VGPR across 64 lanes.
// EARLY STOP: once 300 candidates are kept, no later candidate can enter
// the top-300 (descending scores, stable tie-break = lower index), and
// later suppressions only affect j beyond the 300th kept. Branchless hot
// loop: loads are unconditional (rows >= n are zero; index clamp is SALU).
__global__ void k4_scan(const int* __restrict__ n_arr,
                        const uint32_t* __restrict__ mask,
                        const float* __restrict__ score, const int* __restrict__ label,
                        const float* __restrict__ rx1, const float* __restrict__ ry1,
                        const float* __restrict__ rx2, const float* __restrict__ ry2,
                        float* __restrict__ out) {
    int img = blockIdx.x;
    int lane = threadIdx.x;   // 64 threads = 1 wave
    int n = n_arr[img];
    size_t cbase = (size_t)img * NCAND;
    const uint32_t* rowp = mask + cbase * 64 + lane;
    float* outp = out + (size_t)img * NDET * 6;

    uint32_t removed = 0;
    int kcnt = 0;
    constexpr int PF = 32;           // prefetch depth (static indices -> regs)
    uint32_t buf[PF];
#pragma unroll
    for (int k = 0; k < PF; ++k) buf[k] = rowp[(size_t)k * 64];
    for (int ib = 0; ib < n; ib += PF) {
#pragma unroll
        for (int k = 0; k < PF; ++k) {
            int i = ib + k;
            uint32_t row = buf[k];
            int pi = i + PF; if (pi > NCAND - 1) pi = NCAND - 1;  // uniform, SALU
            buf[k] = rowp[(size_t)pi * 64];     // clamped dup never consumed
            // kept(i)?  bit for i lives at lane (i&63), bit (i>>6). i uniform.
            uint32_t w = (uint32_t)__builtin_amdgcn_readlane((int)removed, i & 63);
            uint32_t kept = ((w >> (i >> 6)) & 1u) ^ 1u;
            kcnt += (int)kept;                   // scalar (phantom i>=n harmless)
            removed |= row & (0u - kept);        // row==0 when i>=n -> no-op
        }
        if (kcnt >= NDET) break;                 // uniform early stop
    }

    // Emit kept candidates in sorted order (rank = #kept with smaller j).
    int bsum = 0;
    for (int b = 0; b < 32; ++b) {
        int j = lane + (b << 6);
        bool kept = (j < n) && (((removed >> b) & 1u) == 0u);
        unsigned long long m64 = __ballot(kept);
        if (kept) {
            int r = bsum + (int)__popcll(m64 & ((1ull << lane) - 1ull));
            if (r < NDET) {
                float* o = outp + (size_t)r * 6;
                o[0] = rx1[cbase + j]; o[1] = ry1[cbase + j];
                o[2] = rx2[cbase + j]; o[3] = ry2[cbase + j];
                o[4] = score[cbase + j]; o[5] = (float)label[cbase + j];
            }
        }
        bsum += (int)__popcll(m64);
        if (bsum >= NDET) break;         // uniform across the wave
    }
    int nk = bsum < NDET ? bsum : NDET;
    for (int idx = nk * 6 + lane; idx < NDET * 6; idx += 64) outp[idx] = 0.0f;
}

// ---------------- launch ----------------
extern "C" void kernel_launch(void* const* d_in, const int* in_sizes, int n_in,
                              void* d_out, int out_size, void* d_ws, size_t ws_size,
                              hipStream_t stream) {
    const float* pred = (const float*)d_in[0];
    float* out = (float*)d_out;
    char* w = (char*)d_ws;

    const size_t A_CNT = 0;                                // 8*32 ints (padded)
    const size_t A_N   = 1024;                             // 8 ints
    const size_t A_RS  = 1280;
    const size_t SZ_RAW = (size_t)NIMG * CAPRAW * 4;       // 128 KiB
    const size_t A_RF  = A_RS + SZ_RAW;
    const size_t SA    = A_RF + SZ_RAW;
    const size_t SZ_S  = (size_t)NIMG * NCAND * 4;         // 64 KiB each

    int*   cnt   = (int*)(w + A_CNT);
    int*   n_arr = (int*)(w + A_N);
    float* raw_s = (float*)(w + A_RS);
    int*   raw_f = (int*)(w + A_RF);
    float* score = (float*)(w + SA + 0 * SZ_S);
    int*   label = (int*)(w + SA + 1 * SZ_S);
    float* ox1   = (float*)(w + SA + 2 * SZ_S);
    float* oy1   = (float*)(w + SA + 3 * SZ_S);
    float* ox2   = (float*)(w + SA + 4 * SZ_S);
    float* oy2   = (float*)(w + SA + 5 * SZ_S);
    float* area  = (float*)(w + SA + 6 * SZ_S);
    float* rx1   = (float*)(w + SA + 7 * SZ_S);
    float* ry1   = (float*)(w + SA + 8 * SZ_S);
    float* rx2   = (float*)(w + SA + 9 * SZ_S);
    float* ry2   = (float*)(w + SA + 10 * SZ_S);
    uint32_t* mask = (uint32_t*)(w + SA + 11 * SZ_S);      // 8*2048*64*4 = 4 MiB

    k0_zero<<<1, NIMG * CSTRIDE, 0, stream>>>(cnt);
    dim3 g1(NA / APB, NIMG);                               // 225 x 8
    k1_filter<<<g1, 256, 0, stream>>>(pred, cnt, raw_s, raw_f);
    k2_sort<<<NIMG, 1024, 0, stream>>>(pred, cnt, n_arr, raw_s, raw_f,
        score, label, ox1, oy1, ox2, oy2, area, rx1, ry1, rx2, ry2);
    dim3 g3(NCAND, NIMG);
    k3_mask<<<g3, 64, 0, stream>>>(n_arr, ox1, oy1, ox2, oy2, area, mask);
    k4_scan<<<NIMG, 64, 0, stream>>>(n_arr, mask, score, label,
        rx1, ry1, rx2, ry2, out);
}

// Round 5
// 183.418 us; speedup vs baseline: 2.0803x; 1.0702x over previous
//
#include <hip/hip_runtime.h>
#include <stdint.h>

#define CONF 0.96f
#define IOUT 0.45f
#define NA 25200
#define DIM 85
#define NC 80
#define NIMG 8
#define NCAND 2048
#define CAPRAW 4096
#define NDET 300
#define CSTRIDE 32                    // cnt[img*CSTRIDE]: 128 B between counters

// ---------------- K0: zero per-image candidate counters ----------------
__global__ void k0_zero(int* __restrict__ cnt) {
    cnt[threadIdx.x] = 0;             // launch 256 = NIMG*CSTRIDE
}

// ---------------- K1: coalesced filter, block-aggregated atomics -------
#define APB 112
#define BCAP 256                      // block candidate cap (E=7.3, P(>256)~0)
__global__ __launch_bounds__(256) void k1_filter(
    const float* __restrict__ pred, int* __restrict__ cnt,
    float* __restrict__ raw_s, int* __restrict__ raw_f) {
    __shared__ float lds[APB * DIM];  // 38080 B
    __shared__ float l_s[BCAP];
    __shared__ int   l_f[BCAP];
    __shared__ int   l_cnt, l_base;
    int tid = threadIdx.x;
    int img = blockIdx.y;
    int a0 = blockIdx.x * APB;        // anchor base within this image
    if (tid == 0) l_cnt = 0;

    const float4* src = (const float4*)(pred + ((size_t)img * NA + a0) * DIM);
    float4* dst = (float4*)lds;
    for (int i = tid; i < (APB * DIM / 4); i += 256) dst[i] = src[i];
    __syncthreads();

    // 112*80 = 8960 items over 256 threads (35 iters)
    for (int it = 0; it < (APB * NC / 256); ++it) {
        int w = tid + it * 256;
        int al = w / NC;              // local anchor
        int c = w - al * NC;          // class
        float obj = lds[al * DIM + 4];
        float s = lds[al * DIM + 5 + c] * obj;
        if (s > CONF && obj > CONF) {
            int p = atomicAdd(&l_cnt, 1);          // LDS atomic: cheap
            if (p < BCAP) { l_s[p] = s; l_f[p] = (a0 + al) * NC + c; }
        }
    }
    __syncthreads();
    int c = l_cnt; if (c > BCAP) c = BCAP;
    if (tid == 0) l_base = c ? atomicAdd(&cnt[img * CSTRIDE], c) : 0;
    __syncthreads();
    int base = l_base;
    for (int i = tid; i < c; i += 256) {
        int pos = base + i;
        if (pos < CAPRAW) {
            raw_s[img * CAPRAW + pos] = l_s[i];
            raw_f[img * CAPRAW + pos] = l_f[i];
        }
    }
}

// ---------------- K2: O(n^2) rank sort (replaces bitonic) --------------
// Keys distinct (flat idx in low bits) -> rank_i = #{key_j > key_i} is a
// permutation; scatter to rank = exact descending sort, identical tie
// semantics to top_k (score desc, flat idx asc). One candidate per lane,
// 64 blocks/img; ~26 active blocks/img spread over CUs. Inner loop: tile
// of 64 keys in lane regs (prefetch 1 ahead), broadcast via v_readlane
// (uniform idx), compare. No LDS, no barriers.
__global__ __launch_bounds__(64) void k2_rank(
    const float* __restrict__ pred,
    const int* __restrict__ cnt, int* __restrict__ n_arr,
    const float* __restrict__ raw_s, const int* __restrict__ raw_f,
    float* __restrict__ score, int* __restrict__ label,
    float* __restrict__ ox1, float* __restrict__ oy1,
    float* __restrict__ ox2, float* __restrict__ oy2,
    float* __restrict__ area,
    float* __restrict__ rx1, float* __restrict__ ry1,
    float* __restrict__ rx2, float* __restrict__ ry2) {
    int img = blockIdx.y;
    int lane = threadIdx.x;
    int m = cnt[img * CSTRIDE]; if (m > CAPRAW) m = CAPRAW;
    if (blockIdx.x == 0 && lane == 0) n_arr[img] = m < NCAND ? m : NCAND;
    int idx = blockIdx.x * 64 + lane;
    if (blockIdx.x * 64 >= m) return;            // uniform early exit

    const float* rs = raw_s + img * CAPRAW;
    const int*   rf = raw_f + img * CAPRAW;
    bool valid = idx < m;
    uint64_t my = 0;
    uint32_t myf = 0;
    if (valid) {
        float s = rs[idx];
        myf = (uint32_t)rf[idx];
        my = ((uint64_t)__float_as_uint(s) << 32) | (uint32_t)(~myf);
    }

    int ntile = (m + 63) >> 6;
    // load tile 0
    uint64_t cur = 0;
    {
        int j = lane;
        if (j < m) cur = ((uint64_t)__float_as_uint(rs[j]) << 32) | (uint32_t)(~(uint32_t)rf[j]);
    }
    int rank = 0;
    for (int t = 0; t < ntile; ++t) {
        // prefetch next tile while comparing current
        uint64_t nxt = 0;
        int jn = ((t + 1) << 6) + lane;
        if (t + 1 < ntile && jn < m)
            nxt = ((uint64_t)__float_as_uint(rs[jn]) << 32) | (uint32_t)(~(uint32_t)rf[jn]);
        int tlo = (int)(uint32_t)cur;
        int thi = (int)(uint32_t)(cur >> 32);
#pragma unroll 16
        for (int i = 0; i < 64; ++i) {
            uint32_t blo = (uint32_t)__builtin_amdgcn_readlane(tlo, i);
            uint32_t bhi = (uint32_t)__builtin_amdgcn_readlane(thi, i);
            uint64_t bk = ((uint64_t)bhi << 32) | blo;
            rank += (bk > my) ? 1 : 0;           // pad keys (0) never count
        }
        cur = nxt;
    }

    if (valid && rank < NCAND) {
        float s = __uint_as_float((uint32_t)(my >> 32));
        int anchor = (int)(myf / NC);
        int lab = (int)(myf - (uint32_t)anchor * NC);
        const float* p = pred + ((size_t)img * NA + anchor) * DIM;
        float cx = p[0], cy = p[1], wv = p[2], hv = p[3];
        float x1 = cx - 0.5f * wv, y1 = cy - 0.5f * hv;
        float x2 = cx + 0.5f * wv, y2 = cy + 0.5f * hv;
        float off = (float)lab * 4.0f;
        size_t o = (size_t)img * NCAND + rank;
        score[o] = s; label[o] = lab;
        rx1[o] = x1; ry1[o] = y1; rx2[o] = x2; ry2[o] = y2;
        float o1 = x1 + off, o2 = y1 + off, o3 = x2 + off, o4 = y2 + off;
        ox1[o] = o1; oy1[o] = o2; ox2[o] = o3; oy2[o] = o4;
        area[o] = (o3 - o1) * (o4 - o2);   // same op order as reference
    }
}

// ---------------- K3: suppression bitmask matrix -----------------------
// Interleaved ownership: lane L, bit b  <->  j = L + 64*b.
// Rows i >= n are ZERO-FILLED (k4 loads unconditionally).
__global__ void k3_mask(const int* __restrict__ n_arr,
                        const float* __restrict__ ox1, const float* __restrict__ oy1,
                        const float* __restrict__ ox2, const float* __restrict__ oy2,
                        const float* __restrict__ area, uint32_t* __restrict__ mask) {
    int img = blockIdx.y;
    int i = blockIdx.x;
    int n = n_arr[img];
    int lane = threadIdx.x;
    size_t base = (size_t)img * NCAND;
    uint32_t word = 0;
    if (i < n) {
        float ax1 = ox1[base + i], ay1 = oy1[base + i];
        float ax2 = ox2[base + i], ay2 = oy2[base + i];
        float aar = area[base + i];
        for (int b = 0; b < 32; ++b) {
            int j = lane + (b << 6);
            if (j < n && j > i) {
                float bx1 = ox1[base + j], by1 = oy1[base + j];
                float bx2 = ox2[base + j], by2 = oy2[base + j];
                float bar = area[base + j];
                float ltx = fmaxf(ax1, bx1), lty = fmaxf(ay1, by1);
                float rbx = fminf(ax2, bx2), rby = fminf(ay2, by2);
                float wv = fmaxf(rbx - ltx, 0.0f), hv = fmaxf(rby - lty, 0.0f);
                float inter = wv * hv;
                float iou = inter / (aar + bar - inter + 1e-9f);
                if (iou > IOUT) word |= (1u << b);
            }
        }
    }
    mask[((size_t)img * NCAND + i) * 64 + lane] = word;
}

// ---------------- K4: serial greedy scan + top-300 output --------------
// One wave per image; early stop at 300 kept (see R3 notes).
__global__ void k4_scan(const int* __restrict__ n_arr,
                        const uint32_t* __restrict__ mask,
                        const float* __restrict__ score, const int* __restrict__ label,
                        const float* __restrict__ rx1, const float* __restrict__ ry1,
                        const float* __restrict__ rx2, const float* __restrict__ ry2,
                        float* __restrict__ out) {
    int img = blockIdx.x;
    int lane = threadIdx.x;   // 64 threads = 1 wave
    int n = n_arr[img];
    size_t cbase = (size_t)img * NCAND;
    const uint32_t* rowp = mask + cbase * 64 + lane;
    float* outp = out + (size_t)img * NDET * 6;

    uint32_t removed = 0;
    int kcnt = 0;
    constexpr int PF = 32;           // prefetch depth (static indices -> regs)
    uint32_t buf[PF];
#pragma unroll
    for (int k = 0; k < PF; ++k) buf[k] = rowp[(size_t)k * 64];
    for (int ib = 0; ib < n; ib += PF) {
#pragma unroll
        for (int k = 0; k < PF; ++k) {
            int i = ib + k;
            uint32_t row = buf[k];
            int pi = i + PF; if (pi > NCAND - 1) pi = NCAND - 1;  // uniform, SALU
            buf[k] = rowp[(size_t)pi * 64];     // clamped dup never consumed
            uint32_t w = (uint32_t)__builtin_amdgcn_readlane((int)removed, i & 63);
            uint32_t kept = ((w >> (i >> 6)) & 1u) ^ 1u;
            kcnt += (int)kept;                   // scalar (phantom i>=n harmless)
            removed |= row & (0u - kept);        // row==0 when i>=n -> no-op
        }
        if (kcnt >= NDET) break;                 // uniform early stop
    }

    // Emit kept candidates in sorted order (rank = #kept with smaller j).
    int bsum = 0;
    for (int b = 0; b < 32; ++b) {
        int j = lane + (b << 6);
        bool kept = (j < n) && (((removed >> b) & 1u) == 0u);
        unsigned long long m64 = __ballot(kept);
        if (kept) {
            int r = bsum + (int)__popcll(m64 & ((1ull << lane) - 1ull));
            if (r < NDET) {
                float* o = outp + (size_t)r * 6;
                o[0] = rx1[cbase + j]; o[1] = ry1[cbase + j];
                o[2] = rx2[cbase + j]; o[3] = ry2[cbase + j];
                o[4] = score[cbase + j]; o[5] = (float)label[cbase + j];
            }
        }
        bsum += (int)__popcll(m64);
        if (bsum >= NDET) break;         // uniform across the wave
    }
    int nk = bsum < NDET ? bsum : NDET;
    for (int idx = nk * 6 + lane; idx < NDET * 6; idx += 64) outp[idx] = 0.0f;
}

// ---------------- launch ----------------
extern "C" void kernel_launch(void* const* d_in, const int* in_sizes, int n_in,
                              void* d_out, int out_size, void* d_ws, size_t ws_size,
                              hipStream_t stream) {
    const float* pred = (const float*)d_in[0];
    float* out = (float*)d_out;
    char* w = (char*)d_ws;

    const size_t A_CNT = 0;                                // 8*32 ints (padded)
    const size_t A_N   = 1024;                             // 8 ints
    const size_t A_RS  = 1280;
    const size_t SZ_RAW = (size_t)NIMG * CAPRAW * 4;       // 128 KiB
    const size_t A_RF  = A_RS + SZ_RAW;
    const size_t SA    = A_RF + SZ_RAW;
    const size_t SZ_S  = (size_t)NIMG * NCAND * 4;         // 64 KiB each

    int*   cnt   = (int*)(w + A_CNT);
    int*   n_arr = (int*)(w + A_N);
    float* raw_s = (float*)(w + A_RS);
    int*   raw_f = (int*)(w + A_RF);
    float* score = (float*)(w + SA + 0 * SZ_S);
    int*   label = (int*)(w + SA + 1 * SZ_S);
    float* ox1   = (float*)(w + SA + 2 * SZ_S);
    float* oy1   = (float*)(w + SA + 3 * SZ_S);
    float* ox2   = (float*)(w + SA + 4 * SZ_S);
    float* oy2   = (float*)(w + SA + 5 * SZ_S);
    float* area  = (float*)(w + SA + 6 * SZ_S);
    float* rx1   = (float*)(w + SA + 7 * SZ_S);
    float* ry1   = (float*)(w + SA + 8 * SZ_S);
    float* rx2   = (float*)(w + SA + 9 * SZ_S);
    float* ry2   = (float*)(w + SA + 10 * SZ_S);
    uint32_t* mask = (uint32_t*)(w + SA + 11 * SZ_S);      // 8*2048*64*4 = 4 MiB

    k0_zero<<<1, NIMG * CSTRIDE, 0, stream>>>(cnt);
    dim3 g1(NA / APB, NIMG);                               // 225 x 8
    k1_filter<<<g1, 256, 0, stream>>>(pred, cnt, raw_s, raw_f);
    dim3 g2(CAPRAW / 64, NIMG);                            // 64 x 8
    k2_rank<<<g2, 64, 0, stream>>>(pred, cnt, n_arr, raw_s, raw_f,
        score, label, ox1, oy1, ox2, oy2, area, rx1, ry1, rx2, ry2);
    dim3 g3(NCAND, NIMG);
    k3_mask<<<g3, 64, 0, stream>>>(n_arr, ox1, oy1, ox2, oy2, area, mask);
    k4_scan<<<NIMG, 64, 0, stream>>>(n_arr, mask, score, label,
        rx1, ry1, rx2, ry2, out);
}